// Round 3
// baseline (279.340 us; speedup 1.0000x reference)
//
#include <hip/hip_runtime.h>

#define NN 8192      // nodes
#define NE 262144    // edges
#define DIM 128
#define BCAP 128     // bucket capacity per node (deg ~ Poisson(32), 128 is >6 sigma)

typedef float f32x4 __attribute__((ext_vector_type(4)));

__device__ __forceinline__ float4 f4fma(float s, float4 w, float4 acc) {
    acc.x = fmaf(s, w.x, acc.x);
    acc.y = fmaf(s, w.y, acc.y);
    acc.z = fmaf(s, w.z, acc.z);
    acc.w = fmaf(s, w.w, acc.w);
    return acc;
}
__device__ __forceinline__ float f4dot(float4 a, float4 b) {
    return fmaf(a.x, b.x, fmaf(a.y, b.y, fmaf(a.z, b.z, a.w * b.w)));
}

// ---------------- K1: zero cnt (blocks 0..31) + u/v/beta (block 32) ----------------
__global__ __launch_bounds__(256) void init_kernel(const float* __restrict__ Wout,
                                                   const float* __restrict__ bout,
                                                   const float* __restrict__ we,
                                                   const float* __restrict__ bedge,
                                                   int* __restrict__ cnt,
                                                   float* __restrict__ u,
                                                   float* __restrict__ v,
                                                   float* __restrict__ beta) {
    int k = threadIdx.x;
    if (blockIdx.x < 32) {
        cnt[blockIdx.x * 256 + k] = 0;
        return;
    }
    // block 32: u[k] = Wout[k,:] . we[:128], v[k] = Wout[k,:] . we[128:]
    if (k < DIM) {
        const float4* W4 = (const float4*)(Wout + (k << 7));
        const float4* we4 = (const float4*)we;
        float su = 0.f, sv = 0.f;
#pragma unroll
        for (int j = 0; j < 32; ++j) {
            float4 w = W4[j];
            su += f4dot(w, we4[j]);
            sv += f4dot(w, we4[32 + j]);
        }
        u[k] = su;
        v[k] = sv;
    }
    __shared__ float red[256];
    red[k] = (k < DIM) ? bout[k] * we[k] : 0.f;
    __syncthreads();
    for (int off = 128; off >= 1; off >>= 1) {
        if (k < off) red[k] += red[k + off];
        __syncthreads();
    }
    float b0 = red[0];  // all threads read after barrier loop (k==0 valid; others don't care)
    __syncthreads();
    red[k] = (k < DIM) ? bout[k] * we[DIM + k] : 0.f;
    __syncthreads();
    for (int off = 128; off >= 1; off >>= 1) {
        if (k < off) red[k] += red[k + off];
        __syncthreads();
    }
    if (k == 0) {
        beta[0] = b0 + bedge[0];
        beta[1] = red[0];
    }
}

// ---------------- K2: scatter edges into fixed-capacity buckets; cnt ends as indegree ----------------
__global__ __launch_bounds__(256) void scatter_kernel(const int* __restrict__ src,
                                                      const int* __restrict__ dst,
                                                      int* __restrict__ cnt,
                                                      int* __restrict__ bucket) {
    int e = blockIdx.x * 256 + threadIdx.x;
    int d = dst[e];
    int p = atomicAdd(&cnt[d], 1);
    if (p < BCAP) bucket[(d << 7) + p] = src[e];
}

// ---------------- K3/K5: aggregation. one wave per node; lane holds 2 of 128 features ----------------
// FIRST=1: in = raw features -> per-edge scale rsqrt(deg_s+1), self scaled by dv_d.
// FIRST=0: in rows already prescaled by their dinv.
template <int FIRST>
__global__ __launch_bounds__(256) void agg_kernel(const float* __restrict__ in,
                                                  const int* __restrict__ cnt,
                                                  const int* __restrict__ bucket,
                                                  float* __restrict__ out) {
    int node = blockIdx.x * 4 + (threadIdx.x >> 6);
    int lane = threadIdx.x & 63;
    const float2* in2 = (const float2*)in;
    int deg = cnt[node];
    float dv_d = rsqrtf((float)(deg + 1));
    float2 self = in2[node * 64 + lane];
    float ax, ay;
    if (FIRST) { ax = self.x * dv_d; ay = self.y * dv_d; }
    else       { ax = self.x;        ay = self.y; }
    const int* bk = bucket + (node << 7);
    int e = 0;
    for (; e + 2 <= deg; e += 2) {
        int s0 = bk[e], s1 = bk[e + 1];
        float2 t0 = in2[s0 * 64 + lane];
        float2 t1 = in2[s1 * 64 + lane];
        if (FIRST) {
            float w0 = rsqrtf((float)(cnt[s0] + 1));
            float w1 = rsqrtf((float)(cnt[s1] + 1));
            ax = fmaf(t0.x, w0, ax); ay = fmaf(t0.y, w0, ay);
            ax = fmaf(t1.x, w1, ax); ay = fmaf(t1.y, w1, ay);
        } else {
            ax += t0.x + t1.x;
            ay += t0.y + t1.y;
        }
    }
    if (e < deg) {
        int s0 = bk[e];
        float2 t0 = in2[s0 * 64 + lane];
        float w0 = FIRST ? rsqrtf((float)(cnt[s0] + 1)) : 1.f;
        ax = fmaf(t0.x, w0, ax);
        ay = fmaf(t0.y, w0, ay);
    }
    float2 o;
    o.x = ax * dv_d;
    o.y = ay * dv_d;
    ((float2*)out)[node * 64 + lane] = o;
}

// ---------------- K4/K6: GEMM 8192x128 @ 128x128 with fused epilogues ----------------
// LAYER=1: H[r][c] = relu(acc + b[c]) * rsqrt(cnt[r]+1)   (prescale for next agg)
// LAYER=2: t = relu(acc + b[c]); a[r] = t.u + beta0, c[r] = t.v + beta1 (shfl-reduce over tx)
template <int LAYER>
__global__ __launch_bounds__(256) void gemm_kernel(const float* __restrict__ X,
                                                   const float* __restrict__ W,
                                                   const float* __restrict__ bias,
                                                   const int* __restrict__ cnt,
                                                   float* __restrict__ H,
                                                   const float* __restrict__ u,
                                                   const float* __restrict__ v,
                                                   const float* __restrict__ beta,
                                                   float* __restrict__ a,
                                                   float* __restrict__ c) {
    __shared__ float4 Wl[128 * 32];  // [k][c4]  64KB
    __shared__ float4 Xl[32 * 32];   // [r][k4]  16KB
    int tid = threadIdx.x;
    int rbase = blockIdx.x * 32;

    const float4* W4 = (const float4*)W;
#pragma unroll
    for (int i = 0; i < 16; ++i) Wl[i * 256 + tid] = W4[i * 256 + tid];
    const float4* X4 = (const float4*)(X + rbase * DIM);
#pragma unroll
    for (int i = 0; i < 4; ++i) Xl[i * 256 + tid] = X4[i * 256 + tid];
    __syncthreads();

    int tx = tid & 31;  // cols tx*4..tx*4+3
    int ty = tid >> 5;  // rows ty*4..ty*4+3
    float4 acc[4];
#pragma unroll
    for (int i = 0; i < 4; ++i) acc[i] = make_float4(0.f, 0.f, 0.f, 0.f);

    for (int k4 = 0; k4 < 32; ++k4) {
        float4 w0 = Wl[(k4 * 4 + 0) * 32 + tx];
        float4 w1 = Wl[(k4 * 4 + 1) * 32 + tx];
        float4 w2 = Wl[(k4 * 4 + 2) * 32 + tx];
        float4 w3 = Wl[(k4 * 4 + 3) * 32 + tx];
#pragma unroll
        for (int i = 0; i < 4; ++i) {
            float4 xv = Xl[(ty * 4 + i) * 32 + k4];
            acc[i] = f4fma(xv.x, w0, acc[i]);
            acc[i] = f4fma(xv.y, w1, acc[i]);
            acc[i] = f4fma(xv.z, w2, acc[i]);
            acc[i] = f4fma(xv.w, w3, acc[i]);
        }
    }

    float4 bb = ((const float4*)bias)[tx];
    if (LAYER == 1) {
        float4* H4 = (float4*)H;
#pragma unroll
        for (int i = 0; i < 4; ++i) {
            int r = rbase + ty * 4 + i;
            float di = rsqrtf((float)(cnt[r] + 1));
            float4 o;
            o.x = fmaxf(acc[i].x + bb.x, 0.f) * di;
            o.y = fmaxf(acc[i].y + bb.y, 0.f) * di;
            o.z = fmaxf(acc[i].z + bb.z, 0.f) * di;
            o.w = fmaxf(acc[i].w + bb.w, 0.f) * di;
            H4[r * 32 + tx] = o;
        }
    } else {
        float4 uu = ((const float4*)u)[tx];
        float4 vv = ((const float4*)v)[tx];
        float b0 = beta[0], b1 = beta[1];
#pragma unroll
        for (int i = 0; i < 4; ++i) {
            float4 t;
            t.x = fmaxf(acc[i].x + bb.x, 0.f);
            t.y = fmaxf(acc[i].y + bb.y, 0.f);
            t.z = fmaxf(acc[i].z + bb.z, 0.f);
            t.w = fmaxf(acc[i].w + bb.w, 0.f);
            float pa = f4dot(t, uu);
            float pc = f4dot(t, vv);
#pragma unroll
            for (int off = 16; off >= 1; off >>= 1) {
                pa += __shfl_xor(pa, off);
                pc += __shfl_xor(pc, off);
            }
            if (tx == 0) {
                int r = rbase + ty * 4 + i;
                a[r] = pa + b0;
                c[r] = pc + b1;
            }
        }
    }
}

// ---------------- K7: out[i][j] = a[i] + c[j] ----------------
__global__ __launch_bounds__(256) void out_kernel(const float* __restrict__ a,
                                                  const float* __restrict__ c,
                                                  f32x4* __restrict__ out) {
    int t = blockIdx.x * 256 + threadIdx.x;  // 4 float4 (64B) per thread
    int i = t >> 9;                          // row: (t*4) / 2048
    int j4 = (t & 511) * 4;
    float av = a[i];
    const f32x4* c4 = (const f32x4*)c;
#pragma unroll
    for (int q = 0; q < 4; ++q) {
        f32x4 r = c4[j4 + q] + av;
        __builtin_nontemporal_store(r, out + (size_t)t * 4 + q);
    }
}

extern "C" void kernel_launch(void* const* d_in, const int* in_sizes, int n_in,
                              void* d_out, int out_size, void* d_ws, size_t ws_size,
                              hipStream_t stream) {
    const float* x    = (const float*)d_in[0];
    const int*   ei   = (const int*)d_in[1];
    const float* W1   = (const float*)d_in[2];
    const float* b1   = (const float*)d_in[3];
    const float* W2   = (const float*)d_in[4];
    const float* b2   = (const float*)d_in[5];
    const float* Wout = (const float*)d_in[6];
    const float* bout = (const float*)d_in[7];
    const float* We   = (const float*)d_in[8];
    const float* bedge= (const float*)d_in[9];
    const int* src = ei;
    const int* dst = ei + NE;

    // workspace
    int* cnt     = (int*)d_ws;                    // 8192
    int* bucket  = cnt + NN;                      // 8192*128
    float* u     = (float*)(bucket + NN * BCAP);  // 128
    float* v     = u + DIM;                       // 128
    float* beta  = v + DIM;                       // 2 (pad 16)
    float* y     = beta + 16;                     // 8192*128 (y1, reused as y2)
    float* h1s   = y + NN * DIM;                  // 8192*128
    float* av    = h1s + NN * DIM;                // 8192
    float* cv    = av + NN;                       // 8192

    float* out = (float*)d_out;

    init_kernel<<<33, 256, 0, stream>>>(Wout, bout, We, bedge, cnt, u, v, beta);
    scatter_kernel<<<NE / 256, 256, 0, stream>>>(src, dst, cnt, bucket);
    agg_kernel<1><<<NN / 4, 256, 0, stream>>>(x, cnt, bucket, y);
    gemm_kernel<1><<<NN / 32, 256, 0, stream>>>(y, W1, b1, cnt, h1s,
                                                nullptr, nullptr, nullptr, nullptr, nullptr);
    agg_kernel<0><<<NN / 4, 256, 0, stream>>>(h1s, cnt, bucket, y);
    gemm_kernel<2><<<NN / 32, 256, 0, stream>>>(y, W2, b2, cnt, nullptr,
                                                u, v, beta, av, cv);
    out_kernel<<<(NN * NN / 16) / 256, 256, 0, stream>>>(av, cv, (f32x4*)out);
}

// Round 4
// 121.139 us; speedup vs baseline: 2.3059x; 2.3059x over previous
//
#include <hip/hip_runtime.h>

#define NN 8192      // nodes
#define NE 262144    // edges
#define DIM 128
#define BCAP 128     // bucket capacity per node (deg ~ Poisson(32), 128 is >6 sigma)

typedef float f32x4 __attribute__((ext_vector_type(4)));

__device__ __forceinline__ float4 f4fma(float s, float4 w, float4 acc) {
    acc.x = fmaf(s, w.x, acc.x);
    acc.y = fmaf(s, w.y, acc.y);
    acc.z = fmaf(s, w.z, acc.z);
    acc.w = fmaf(s, w.w, acc.w);
    return acc;
}
__device__ __forceinline__ float f4dot(float4 a, float4 b) {
    return fmaf(a.x, b.x, fmaf(a.y, b.y, fmaf(a.z, b.z, a.w * b.w)));
}

// ---------------- K1: zero cnt (blocks 0..31) + u/v/beta (block 32) ----------------
__global__ __launch_bounds__(256) void init_kernel(const float* __restrict__ Wout,
                                                   const float* __restrict__ bout,
                                                   const float* __restrict__ we,
                                                   const float* __restrict__ bedge,
                                                   int* __restrict__ cnt,
                                                   float* __restrict__ u,
                                                   float* __restrict__ v,
                                                   float* __restrict__ beta) {
    int k = threadIdx.x;
    if (blockIdx.x < 32) {
        cnt[blockIdx.x * 256 + k] = 0;
        return;
    }
    // block 32: u[k] = Wout[k,:] . we[:128], v[k] = Wout[k,:] . we[128:]
    if (k < DIM) {
        const float4* W4 = (const float4*)(Wout + (k << 7));
        const float4* we4 = (const float4*)we;
        float su = 0.f, sv = 0.f;
#pragma unroll
        for (int j = 0; j < 32; ++j) {
            float4 w = W4[j];
            su += f4dot(w, we4[j]);
            sv += f4dot(w, we4[32 + j]);
        }
        u[k] = su;
        v[k] = sv;
    }
    __shared__ float red[256];
    red[k] = (k < DIM) ? bout[k] * we[k] : 0.f;
    __syncthreads();
    for (int off = 128; off >= 1; off >>= 1) {
        if (k < off) red[k] += red[k + off];
        __syncthreads();
    }
    float b0 = red[0];
    __syncthreads();
    red[k] = (k < DIM) ? bout[k] * we[DIM + k] : 0.f;
    __syncthreads();
    for (int off = 128; off >= 1; off >>= 1) {
        if (k < off) red[k] += red[k + off];
        __syncthreads();
    }
    if (k == 0) {
        beta[0] = b0 + bedge[0];
        beta[1] = red[0];
    }
}

// ---------------- K2: scatter edges into fixed-capacity buckets; cnt ends as indegree ----------------
__global__ __launch_bounds__(256) void scatter_kernel(const int* __restrict__ src,
                                                      const int* __restrict__ dst,
                                                      int* __restrict__ cnt,
                                                      int* __restrict__ bucket) {
    int e = blockIdx.x * 256 + threadIdx.x;
    int d = dst[e];
    int p = atomicAdd(&cnt[d], 1);
    if (p < BCAP) bucket[(d << 7) + p] = src[e];
}

// ---------------- K3/K5: aggregation. one wave per node; lane holds 2 of 128 features ----------------
template <int FIRST>
__global__ __launch_bounds__(256) void agg_kernel(const float* __restrict__ in,
                                                  const int* __restrict__ cnt,
                                                  const int* __restrict__ bucket,
                                                  float* __restrict__ out) {
    int node = blockIdx.x * 4 + (threadIdx.x >> 6);
    int lane = threadIdx.x & 63;
    const float2* in2 = (const float2*)in;
    int deg = cnt[node];
    float dv_d = rsqrtf((float)(deg + 1));
    float2 self = in2[node * 64 + lane];
    float ax, ay;
    if (FIRST) { ax = self.x * dv_d; ay = self.y * dv_d; }
    else       { ax = self.x;        ay = self.y; }
    const int* bk = bucket + (node << 7);
    int e = 0;
    for (; e + 2 <= deg; e += 2) {
        int s0 = bk[e], s1 = bk[e + 1];
        float2 t0 = in2[s0 * 64 + lane];
        float2 t1 = in2[s1 * 64 + lane];
        if (FIRST) {
            float w0 = rsqrtf((float)(cnt[s0] + 1));
            float w1 = rsqrtf((float)(cnt[s1] + 1));
            ax = fmaf(t0.x, w0, ax); ay = fmaf(t0.y, w0, ay);
            ax = fmaf(t1.x, w1, ax); ay = fmaf(t1.y, w1, ay);
        } else {
            ax += t0.x + t1.x;
            ay += t0.y + t1.y;
        }
    }
    if (e < deg) {
        int s0 = bk[e];
        float2 t0 = in2[s0 * 64 + lane];
        float w0 = FIRST ? rsqrtf((float)(cnt[s0] + 1)) : 1.f;
        ax = fmaf(t0.x, w0, ax);
        ay = fmaf(t0.y, w0, ay);
    }
    float2 o;
    o.x = ax * dv_d;
    o.y = ay * dv_d;
    ((float2*)out)[node * 64 + lane] = o;
}

// ---------------- K4/K6: GEMM 8192x128 @ 128x128 with fused epilogues ----------------
template <int LAYER>
__global__ __launch_bounds__(256) void gemm_kernel(const float* __restrict__ X,
                                                   const float* __restrict__ W,
                                                   const float* __restrict__ bias,
                                                   const int* __restrict__ cnt,
                                                   float* __restrict__ H,
                                                   const float* __restrict__ u,
                                                   const float* __restrict__ v,
                                                   const float* __restrict__ beta,
                                                   float* __restrict__ a,
                                                   float* __restrict__ c) {
    __shared__ float4 Wl[128 * 32];  // [k][c4]  64KB
    __shared__ float4 Xl[32 * 32];   // [r][k4]  16KB
    int tid = threadIdx.x;
    int rbase = blockIdx.x * 32;

    const float4* W4 = (const float4*)W;
#pragma unroll
    for (int i = 0; i < 16; ++i) Wl[i * 256 + tid] = W4[i * 256 + tid];
    const float4* X4 = (const float4*)(X + rbase * DIM);
#pragma unroll
    for (int i = 0; i < 4; ++i) Xl[i * 256 + tid] = X4[i * 256 + tid];
    __syncthreads();

    int tx = tid & 31;  // cols tx*4..tx*4+3
    int ty = tid >> 5;  // rows ty*4..ty*4+3
    float4 acc[4];
#pragma unroll
    for (int i = 0; i < 4; ++i) acc[i] = make_float4(0.f, 0.f, 0.f, 0.f);

    for (int k4 = 0; k4 < 32; ++k4) {
        float4 w0 = Wl[(k4 * 4 + 0) * 32 + tx];
        float4 w1 = Wl[(k4 * 4 + 1) * 32 + tx];
        float4 w2 = Wl[(k4 * 4 + 2) * 32 + tx];
        float4 w3 = Wl[(k4 * 4 + 3) * 32 + tx];
#pragma unroll
        for (int i = 0; i < 4; ++i) {
            float4 xv = Xl[(ty * 4 + i) * 32 + k4];
            acc[i] = f4fma(xv.x, w0, acc[i]);
            acc[i] = f4fma(xv.y, w1, acc[i]);
            acc[i] = f4fma(xv.z, w2, acc[i]);
            acc[i] = f4fma(xv.w, w3, acc[i]);
        }
    }

    float4 bb = ((const float4*)bias)[tx];
    if (LAYER == 1) {
        float4* H4 = (float4*)H;
#pragma unroll
        for (int i = 0; i < 4; ++i) {
            int r = rbase + ty * 4 + i;
            float di = rsqrtf((float)(cnt[r] + 1));
            float4 o;
            o.x = fmaxf(acc[i].x + bb.x, 0.f) * di;
            o.y = fmaxf(acc[i].y + bb.y, 0.f) * di;
            o.z = fmaxf(acc[i].z + bb.z, 0.f) * di;
            o.w = fmaxf(acc[i].w + bb.w, 0.f) * di;
            H4[r * 32 + tx] = o;
        }
    } else {
        float4 uu = ((const float4*)u)[tx];
        float4 vv = ((const float4*)v)[tx];
        float b0 = beta[0], b1 = beta[1];
#pragma unroll
        for (int i = 0; i < 4; ++i) {
            float4 t;
            t.x = fmaxf(acc[i].x + bb.x, 0.f);
            t.y = fmaxf(acc[i].y + bb.y, 0.f);
            t.z = fmaxf(acc[i].z + bb.z, 0.f);
            t.w = fmaxf(acc[i].w + bb.w, 0.f);
            float pa = f4dot(t, uu);
            float pc = f4dot(t, vv);
#pragma unroll
            for (int off = 16; off >= 1; off >>= 1) {
                pa += __shfl_xor(pa, off);
                pc += __shfl_xor(pc, off);
            }
            if (tx == 0) {
                int r = rbase + ty * 4 + i;
                a[r] = pa + b0;
                c[r] = pc + b1;
            }
        }
    }
}

// ---------------- K7: out[i][j] = a[i] + c[j] ----------------
// 4 float4 per thread, block-strided: every store instruction has consecutive
// lanes writing consecutive float4s (contiguous 1KB per wave per store).
__global__ __launch_bounds__(256) void out_kernel(const float* __restrict__ a,
                                                  const float* __restrict__ c,
                                                  f32x4* __restrict__ out) {
    const f32x4* c4 = (const f32x4*)c;
    size_t base = (size_t)blockIdx.x * 1024 + threadIdx.x;
#pragma unroll
    for (int q = 0; q < 4; ++q) {
        size_t idx = base + q * 256;          // float4 index
        int i = (int)(idx >> 11);             // row (2048 float4 per row)
        int j4 = (int)(idx & 2047);
        f32x4 r = c4[j4] + a[i];
        __builtin_nontemporal_store(r, out + idx);
    }
}

extern "C" void kernel_launch(void* const* d_in, const int* in_sizes, int n_in,
                              void* d_out, int out_size, void* d_ws, size_t ws_size,
                              hipStream_t stream) {
    const float* x    = (const float*)d_in[0];
    const int*   ei   = (const int*)d_in[1];
    const float* W1   = (const float*)d_in[2];
    const float* b1   = (const float*)d_in[3];
    const float* W2   = (const float*)d_in[4];
    const float* b2   = (const float*)d_in[5];
    const float* Wout = (const float*)d_in[6];
    const float* bout = (const float*)d_in[7];
    const float* We   = (const float*)d_in[8];
    const float* bedge= (const float*)d_in[9];
    const int* src = ei;
    const int* dst = ei + NE;

    // workspace
    int* cnt     = (int*)d_ws;                    // 8192
    int* bucket  = cnt + NN;                      // 8192*128
    float* u     = (float*)(bucket + NN * BCAP);  // 128
    float* v     = u + DIM;                       // 128
    float* beta  = v + DIM;                       // 2 (pad 16)
    float* y     = beta + 16;                     // 8192*128 (y1, reused as y2)
    float* h1s   = y + NN * DIM;                  // 8192*128
    float* av    = h1s + NN * DIM;                // 8192
    float* cv    = av + NN;                       // 8192

    float* out = (float*)d_out;

    init_kernel<<<33, 256, 0, stream>>>(Wout, bout, We, bedge, cnt, u, v, beta);
    scatter_kernel<<<NE / 256, 256, 0, stream>>>(src, dst, cnt, bucket);
    agg_kernel<1><<<NN / 4, 256, 0, stream>>>(x, cnt, bucket, y);
    gemm_kernel<1><<<NN / 32, 256, 0, stream>>>(y, W1, b1, cnt, h1s,
                                                nullptr, nullptr, nullptr, nullptr, nullptr);
    agg_kernel<0><<<NN / 4, 256, 0, stream>>>(h1s, cnt, bucket, y);
    gemm_kernel<2><<<NN / 32, 256, 0, stream>>>(y, W2, b2, cnt, nullptr,
                                                u, v, beta, av, cv);
    out_kernel<<<(NN * NN / 4) / 1024, 256, 0, stream>>>(av, cv, (f32x4*)out);
}